// Round 18
// baseline (3204.557 us; speedup 1.0000x reference)
//
#include <hip/hip_runtime.h>

// D-MPNN (chemprop) x3 encoders on MI355X.
// R18: phase reorder for occupancy. Only aR (4 acc) live before gather;
//     gather runs with NO accumulators live; aZ/aH computed after (K=128
//     hmF re-read L2-hot + K=256 sums). Peak regs ~110 -> ~80, so
//     launch_bounds(512,6) -> 3 blocks/CU (24 waves). Same math order.

#define NE 100000   // messages
#define NN 50000    // nodes
#define L2E 1.4426950408889634f

typedef unsigned short u16;
typedef short short8 __attribute__((ext_vector_type(8)));
typedef float f32x4 __attribute__((ext_vector_type(4)));
typedef float floatx4 __attribute__((ext_vector_type(4)));
typedef unsigned short u16x4 __attribute__((ext_vector_type(4)));

__device__ __forceinline__ float b2f(u16 u) {
  union { unsigned int i; float f; } v; v.i = ((unsigned int)u) << 16; return v.f;
}
__device__ __forceinline__ u16 f2b(float f) {
  union { float f; unsigned int i; } v; v.f = f;
  unsigned int b = v.i;
  b += 0x7FFFu + ((b >> 16) & 1u);   // RTNE
  return (u16)(b >> 16);
}
__device__ __forceinline__ unsigned cvtpk(float lo, float hi) {
  unsigned r;
  asm("v_cvt_pk_bf16_f32 %0, %1, %2" : "=v"(r) : "v"(lo), "v"(hi));
  return r;
}
// arg prescaled by log2e
__device__ __forceinline__ float sigm2(float x) {
  return __builtin_amdgcn_rcpf(1.0f + __builtin_amdgcn_exp2f(-x));
}
// arg prescaled by 2*log2e
__device__ __forceinline__ float tanh2(float x) {
  return 2.0f * __builtin_amdgcn_rcpf(1.0f + __builtin_amdgcn_exp2f(-x)) - 1.0f;
}
__device__ __forceinline__ f32x4 mfma16(short8 a, short8 b, f32x4 c) {
  return __builtin_amdgcn_mfma_f32_16x16x32_bf16(a, b, c, 0, 0, 0);
}

// ---------------- weight packing (fragment-major, log2e-scaled) ----------------
__global__ void pack_wpre(const float* __restrict__ Wr, const float* __restrict__ Wz,
                          const float* __restrict__ Wh, u16* __restrict__ dst) {
  const int g = blockIdx.y;
  const int p = blockIdx.x * 256 + threadIdx.x;           // < 98304  (K=128,N=768)
  const int j = p & 7, l = (p >> 3) & 63, q = p >> 9;
  const int nb = q % 48, s = q / 48;
  const int k = 32 * s + 8 * (l >> 4) + j;
  const int n = 16 * nb + (l & 15);
  float v = 0.f;
  if (k < 104) {
    if (n < 256)      v = Wr[((size_t)g * 104 + k) * 256 + n] * L2E;
    else if (n < 512) v = Wz[((size_t)g * 360 + k) * 256 + (n - 256)] * L2E;
    else              v = Wh[((size_t)g * 360 + k) * 256 + (n - 512)] * (2.0f * L2E);
  }
  dst[(size_t)g * 98304 + p] = f2b(v);
}

__global__ void pack_wgate(const float* __restrict__ Wz, const float* __restrict__ Wh,
                           u16* __restrict__ dst) {
  const int g = blockIdx.y;
  const int p = blockIdx.x * 256 + threadIdx.x;           // < 131072 (K=256,N=512)
  const int j = p & 7, l = (p >> 3) & 63, q = p >> 9;
  const int nb = q % 32, s = q / 32;
  const int k = 32 * s + 8 * (l >> 4) + j;
  const int n = 16 * nb + (l & 15);
  float v = (n < 256) ? Wz[((size_t)g * 360 + 104 + k) * 256 + n] * L2E
                      : Wh[((size_t)g * 360 + 104 + k) * 256 + (n - 256)] * (2.0f * L2E);
  dst[(size_t)g * 131072 + p] = f2b(v);
}

__global__ void pack_ur(const float* __restrict__ Ur, u16* __restrict__ dst) {
  const int g = blockIdx.y;
  const int p = blockIdx.x * 256 + threadIdx.x;           // < 65536 (K=256,N=256)
  const int j = p & 7, l = (p >> 3) & 63, q = p >> 9;
  const int nb = q % 16, s = q / 16;
  const int k = 32 * s + 8 * (l >> 4) + j;
  const int n = 16 * nb + (l & 15);
  dst[(size_t)g * 65536 + p] = f2b(Ur[((size_t)g * 256 + k) * 256 + n] * L2E);
}

__global__ void pack_wo(const float* __restrict__ Wo, u16* __restrict__ dst) {
  const int g = blockIdx.y;
  const int p = blockIdx.x * 256 + threadIdx.x;           // < 98304 (K=384,N=256)
  const int j = p & 7, l = (p >> 3) & 63, q = p >> 9;
  const int nb = q % 16, s = q / 16;
  const int k = 32 * s + 8 * (l >> 4) + j;
  const int n = 16 * nb + (l & 15);
  float v = 0.f;
  if (k < 98)        v = Wo[((size_t)g * 354 + k) * 256 + n];        // fnode part
  else if (k >= 128) v = Wo[((size_t)g * 354 + (k - 30)) * 256 + n]; // nei part
  dst[(size_t)g * 98304 + p] = f2b(v);
}

// ---------------- embeddings ----------------
__global__ void embed_hmess_f(const float* __restrict__ fnode, const int* __restrict__ fmess_idx,
                              const float* __restrict__ fmess_feat, u16* __restrict__ hmF) {
  const int e = blockIdx.x * 2 + (threadIdx.x >> 7);
  const int c = threadIdx.x & 127;
  const int src = fmess_idx[e * 2];
  float v = 0.f;
  if (c < 98)       v = fnode[(size_t)src * 98 + c];
  else if (c < 104) v = fmess_feat[(size_t)e * 6 + (c - 98)];
  hmF[(size_t)(e >> 4) * 2048 + ((c >> 5) * 64 + (e & 15) + 16 * ((c >> 3) & 3)) * 8 + (c & 7)] = f2b(v);
}

__global__ void embed_fnode(const float* __restrict__ fnode, u16* __restrict__ fnp) {
  const int n = blockIdx.x * 2 + (threadIdx.x >> 7);
  const int c = threadIdx.x & 127;
  float v = (c < 98) ? fnode[(size_t)n * 98 + c] : 0.f;
  fnp[(size_t)n * 128 + c] = f2b(v);
}

// ---------------- fused depth step (32 rows/block) ----------------
// Phase R: r1 only (4 acc). Gather: no acc live. Phase ZH: K=128 hmF part
// then K=256 sums part into aZ/aH (same accumulation order as before).
__global__ __launch_bounds__(512, 6)
void mpn_fused(const u16* __restrict__ HBin, u16* __restrict__ HBout,
               const u16* __restrict__ hmF, const int* __restrict__ bgraph,
               const u16* __restrict__ Wpre, const u16* __restrict__ Wgate,
               const u16* __restrict__ Urp, const float* __restrict__ bur,
               const float* __restrict__ bz, const float* __restrict__ bh) {
  __shared__ __align__(16) u16 sF[16384];    // sh [0,8192), sg [8192,16384)
  const int tid = threadIdx.x;
  const int wn = tid >> 6, lane = tid & 63;
  const int row0 = lane & 15, kq = lane >> 4;
  const int e0 = blockIdx.x * 32;

  // ---- phase R: r1 from hmess (K=128), 4 accumulators only ----
  {
    f32x4 aR[2][2];
#pragma unroll
    for (int nf = 0; nf < 2; ++nf)
#pragma unroll
      for (int ef = 0; ef < 2; ++ef) { aR[nf][ef][0]=0.f; aR[nf][ef][1]=0.f; aR[nf][ef][2]=0.f; aR[nf][ef][3]=0.f; }
#pragma unroll
    for (int kc = 0; kc < 4; ++kc) {
      short8 bm[2];
#pragma unroll
      for (int ef = 0; ef < 2; ++ef)
        bm[ef] = *(const short8*)(hmF + (size_t)((e0 >> 4) + ef) * 2048 + (size_t)(kc * 64 + lane) * 8);
#pragma unroll
      for (int nf = 0; nf < 2; ++nf) {
        short8 wr = *(const short8*)(Wpre + ((size_t)(kc * 48 + wn * 2 + nf) * 64 + lane) * 8);
#pragma unroll
        for (int ef = 0; ef < 2; ++ef)
          aR[nf][ef] = mfma16(wr, bm[ef], aR[nf][ef]);
      }
    }
    // r1 (+bur*L2E) -> sh region of sF, frag layout
#pragma unroll
    for (int nf = 0; nf < 2; ++nf) {
      const int lp = row0 + 16 * (nf * 2 + (kq >> 1));
      const int jo = 4 * (kq & 1);
      const int n = wn * 32 + nf * 16 + kq * 4;
      const floatx4 bv = *(const floatx4*)(bur + n);
#pragma unroll
      for (int ef = 0; ef < 2; ++ef) {
        union { unsigned w[2]; u16x4 q; } pk;
        pk.w[0] = cvtpk(aR[nf][ef][0] + bv[0] * L2E, aR[nf][ef][1] + bv[1] * L2E);
        pk.w[1] = cvtpk(aR[nf][ef][2] + bv[2] * L2E, aR[nf][ef][3] + bv[3] * L2E);
        *(u16x4*)(sF + ef * 4096 + (wn * 64 + lp) * 8 + jo) = pk.q;
      }
    }
  }
  __syncthreads();   // BA: r1 staged

  // ---- gather (no accumulators live); 4 rows/wave ----
  {
    const int c0 = 4 * lane;
    const int offc = ((c0 >> 5) * 64 + 16 * ((c0 >> 3) & 3)) * 8 + (c0 & 7);
#pragma unroll 2
    for (int rr = 0; rr < 4; ++rr) {
      const int r = wn * 4 + rr;
      const int e = e0 + r;
      const int off = (r >> 4) * 4096 + offc + (r & 15) * 8;
      const u16x4 r1v = *(const u16x4*)(sF + off);         // r1 from its own slot
      int idx[6];
#pragma unroll
      for (int k = 0; k < 6; ++k) idx[k] = bgraph[e * 6 + k];
      u16x4 hv[6], huv[6];
#pragma unroll
      for (int k = 0; k < 6; ++k) {
        const u16* rowp = HBin + (size_t)idx[k] * 512;
        hv[k]  = *(const u16x4*)(rowp + c0);
        huv[k] = *(const u16x4*)(rowp + 256 + c0);
      }
      float sh[4] = {0.f, 0.f, 0.f, 0.f}, sg[4] = {0.f, 0.f, 0.f, 0.f};
#pragma unroll
      for (int k = 0; k < 6; ++k)
#pragma unroll
        for (int j = 0; j < 4; ++j) {
          const float h  = b2f(hv[k][j]);
          const float rg = sigm2(b2f(r1v[j]) + b2f(huv[k][j]));
          sh[j] += h;
          sg[j] += rg * h;
        }
      union { unsigned w[2]; u16x4 q; } p0, p1;
      p0.w[0] = cvtpk(sh[0], sh[1]); p0.w[1] = cvtpk(sh[2], sh[3]);
      p1.w[0] = cvtpk(sg[0], sg[1]); p1.w[1] = cvtpk(sg[2], sg[3]);
      *(u16x4*)(sF + off) = p0.q;                          // overwrite r1 with sh
      *(u16x4*)(sF + 8192 + off) = p1.q;
    }
  }
  __syncthreads();   // B0: sF ready

  // ---- phase ZH: K=128 hmF part (L2-hot re-read), then K=256 sums part ----
  f32x4 aZ[2][2], aH[2][2];
#pragma unroll
  for (int nf = 0; nf < 2; ++nf)
#pragma unroll
    for (int ef = 0; ef < 2; ++ef) {
      aZ[nf][ef][0]=0.f; aZ[nf][ef][1]=0.f; aZ[nf][ef][2]=0.f; aZ[nf][ef][3]=0.f;
      aH[nf][ef][0]=0.f; aH[nf][ef][1]=0.f; aH[nf][ef][2]=0.f; aH[nf][ef][3]=0.f;
    }
#pragma unroll
  for (int kc = 0; kc < 4; ++kc) {
    short8 bm[2];
#pragma unroll
    for (int ef = 0; ef < 2; ++ef)
      bm[ef] = *(const short8*)(hmF + (size_t)((e0 >> 4) + ef) * 2048 + (size_t)(kc * 64 + lane) * 8);
#pragma unroll
    for (int nf = 0; nf < 2; ++nf) {
      const int nb = wn * 2 + nf;
      short8 wz = *(const short8*)(Wpre + ((size_t)(kc * 48 + 16 + nb) * 64 + lane) * 8);
      short8 wh = *(const short8*)(Wpre + ((size_t)(kc * 48 + 32 + nb) * 64 + lane) * 8);
#pragma unroll
      for (int ef = 0; ef < 2; ++ef) {
        aZ[nf][ef] = mfma16(wz, bm[ef], aZ[nf][ef]);
        aH[nf][ef] = mfma16(wh, bm[ef], aH[nf][ef]);
      }
    }
  }
#pragma unroll
  for (int kc = 0; kc < 8; ++kc) {
    short8 wz0 = *(const short8*)(Wgate + ((size_t)(kc * 32 + wn * 2 + 0) * 64 + lane) * 8);
    short8 wz1 = *(const short8*)(Wgate + ((size_t)(kc * 32 + wn * 2 + 1) * 64 + lane) * 8);
    short8 wh0 = *(const short8*)(Wgate + ((size_t)(kc * 32 + 16 + wn * 2 + 0) * 64 + lane) * 8);
    short8 wh1 = *(const short8*)(Wgate + ((size_t)(kc * 32 + 16 + wn * 2 + 1) * 64 + lane) * 8);
#pragma unroll
    for (int ef = 0; ef < 2; ++ef) {
      short8 bsh = *(const short8*)(sF + ef * 4096 + (kc * 64 + lane) * 8);
      short8 bsg = *(const short8*)(sF + 8192 + ef * 4096 + (kc * 64 + lane) * 8);
      aZ[0][ef] = mfma16(wz0, bsh, aZ[0][ef]);
      aZ[1][ef] = mfma16(wz1, bsh, aZ[1][ef]);
      aH[0][ef] = mfma16(wh0, bsg, aH[0][ef]);
      aH[1][ef] = mfma16(wh1, bsg, aH[1][ef]);
    }
  }

  // ---- GRU epilogue (scaled fp32 bias; shv from sF) ----
  u16x4 hq[2][2];
#pragma unroll
  for (int nf = 0; nf < 2; ++nf) {
    const int lp = row0 + 16 * (nf * 2 + (kq >> 1));
    const int jo = 4 * (kq & 1);
    const int n = wn * 32 + nf * 16 + kq * 4;
    const floatx4 bzv = *(const floatx4*)(bz + n);
    const floatx4 bhv = *(const floatx4*)(bh + n);
#pragma unroll
    for (int ef = 0; ef < 2; ++ef) {
      const int e = e0 + ef * 16 + row0;
      const int as = ef * 4096 + (wn * 64 + lp) * 8 + jo;
      const u16x4 shv = *(const u16x4*)(sF + as);
      float hf[4];
#pragma unroll
      for (int v = 0; v < 4; ++v) {
        const float z  = sigm2(aZ[nf][ef][v] + bzv[v] * L2E);
        const float ph = tanh2(aH[nf][ef][v] + bhv[v] * (2.0f * L2E));
        float h = (1.0f - z) * b2f(shv[v]) + z * ph;
        if (e == 0) h = 0.f;                  // e_mask
        hf[v] = h;
      }
      union { unsigned w[2]; u16x4 q; } pk;
      pk.w[0] = cvtpk(hf[0], hf[1]);
      pk.w[1] = cvtpk(hf[2], hf[3]);
      hq[nf][ef] = pk.q;
    }
  }
  __syncthreads();   // B1: all sF reads done -> safe to overwrite sg region

  // hnew frag into sg region
#pragma unroll
  for (int nf = 0; nf < 2; ++nf) {
    const int lp = row0 + 16 * (nf * 2 + (kq >> 1));
    const int jo = 4 * (kq & 1);
#pragma unroll
    for (int ef = 0; ef < 2; ++ef)
      *(u16x4*)(sF + 8192 + ef * 4096 + (wn * 64 + lp) * 8 + jo) = hq[nf][ef];
  }
  __syncthreads();   // B2: hnew frag ready

  // ---- hu^T = Urp x hnew (Urp log2e-scaled) ----
  f32x4 aU[2][2];
#pragma unroll
  for (int nf = 0; nf < 2; ++nf)
#pragma unroll
    for (int ef = 0; ef < 2; ++ef) { aU[nf][ef][0]=0.f; aU[nf][ef][1]=0.f; aU[nf][ef][2]=0.f; aU[nf][ef][3]=0.f; }
#pragma unroll
  for (int kc = 0; kc < 8; ++kc) {
    short8 u0 = *(const short8*)(Urp + ((size_t)(kc * 16 + wn * 2 + 0) * 64 + lane) * 8);
    short8 u1 = *(const short8*)(Urp + ((size_t)(kc * 16 + wn * 2 + 1) * 64 + lane) * 8);
#pragma unroll
    for (int ef = 0; ef < 2; ++ef) {
      short8 hb = *(const short8*)(sF + 8192 + ef * 4096 + (kc * 64 + lane) * 8);
      aU[0][ef] = mfma16(u0, hb, aU[0][ef]);
      aU[1][ef] = mfma16(u1, hb, aU[1][ef]);
    }
  }

  // h natural write (sg-region frag -> coalesced rows); 16 threads/row
  {
    const int r = tid >> 4;
    const int e = e0 + r;
#pragma unroll
    for (int it = 0; it < 2; ++it) {
      const int c = (tid & 15) * 8 + it * 128;
      const short8 val = *(const short8*)(sF + 8192 + (r >> 4) * 4096 +
                         (((c >> 5) * 64 + (r & 15) + 16 * ((c >> 3) & 3)) * 8));
      *(short8*)(HBout + (size_t)e * 512 + c) = val;
    }
  }
  // stage hu into sh region (dead since B1)
#pragma unroll
  for (int nf = 0; nf < 2; ++nf) {
    const int lp = row0 + 16 * (nf * 2 + (kq >> 1));
    const int jo = 4 * (kq & 1);
#pragma unroll
    for (int ef = 0; ef < 2; ++ef) {
      union { unsigned w[2]; u16x4 q; } pk;
      pk.w[0] = cvtpk(aU[nf][ef][0], aU[nf][ef][1]);
      pk.w[1] = cvtpk(aU[nf][ef][2], aU[nf][ef][3]);
      *(u16x4*)(sF + ef * 4096 + (wn * 64 + lp) * 8 + jo) = pk.q;
    }
  }
  __syncthreads();   // B3: hu frag ready

  // hu natural write
  {
    const int r = tid >> 4;
    const int e = e0 + r;
#pragma unroll
    for (int it = 0; it < 2; ++it) {
      const int c = (tid & 15) * 8 + it * 128;
      const short8 val = *(const short8*)(sF + (r >> 4) * 4096 +
                         (((c >> 5) * 64 + (r & 15) + 16 * ((c >> 3) & 3)) * 8));
      *(short8*)(HBout + (size_t)e * 512 + 256 + c) = val;
    }
  }
}

// ---------------- depth-0 (32 rows/block) ----------------
__global__ __launch_bounds__(512, 4)
void step0(u16* __restrict__ HB, const u16* __restrict__ hmF,
           const u16* __restrict__ Wpre, const u16* __restrict__ Urp,
           const float* __restrict__ bz, const float* __restrict__ bh) {
  __shared__ __align__(16) u16 sHn[8192];
  const int tid = threadIdx.x;
  const int wn = tid >> 6, lane = tid & 63;
  const int row0 = lane & 15, kq = lane >> 4;
  const int e0 = blockIdx.x * 32;

  f32x4 aZ[2][2], aH[2][2];
#pragma unroll
  for (int nf = 0; nf < 2; ++nf)
#pragma unroll
    for (int ef = 0; ef < 2; ++ef) {
      aZ[nf][ef][0]=0.f; aZ[nf][ef][1]=0.f; aZ[nf][ef][2]=0.f; aZ[nf][ef][3]=0.f;
      aH[nf][ef][0]=0.f; aH[nf][ef][1]=0.f; aH[nf][ef][2]=0.f; aH[nf][ef][3]=0.f;
    }
#pragma unroll
  for (int kc = 0; kc < 4; ++kc) {
    short8 bm[2];
#pragma unroll
    for (int ef = 0; ef < 2; ++ef)
      bm[ef] = *(const short8*)(hmF + (size_t)((e0 >> 4) + ef) * 2048 + (size_t)(kc * 64 + lane) * 8);
#pragma unroll
    for (int nf = 0; nf < 2; ++nf) {
      const int nb = wn * 2 + nf;
      short8 wz = *(const short8*)(Wpre + ((size_t)(kc * 48 + 16 + nb) * 64 + lane) * 8);
      short8 wh = *(const short8*)(Wpre + ((size_t)(kc * 48 + 32 + nb) * 64 + lane) * 8);
#pragma unroll
      for (int ef = 0; ef < 2; ++ef) {
        aZ[nf][ef] = mfma16(wz, bm[ef], aZ[nf][ef]);
        aH[nf][ef] = mfma16(wh, bm[ef], aH[nf][ef]);
      }
    }
  }

#pragma unroll
  for (int nf = 0; nf < 2; ++nf) {
    const int lp = row0 + 16 * (nf * 2 + (kq >> 1));
    const int jo = 4 * (kq & 1);
    const int n = wn * 32 + nf * 16 + kq * 4;
    const floatx4 bzv = *(const floatx4*)(bz + n);
    const floatx4 bhv = *(const floatx4*)(bh + n);
#pragma unroll
    for (int ef = 0; ef < 2; ++ef) {
      const int e = e0 + ef * 16 + row0;
      float hf[4];
#pragma unroll
      for (int v = 0; v < 4; ++v) {
        float h = sigm2(aZ[nf][ef][v] + bzv[v] * L2E) *
                  tanh2(aH[nf][ef][v] + bhv[v] * (2.0f * L2E));
        if (e == 0) h = 0.f;
        hf[v] = h;
      }
      union { unsigned w[2]; u16x4 q; } pk;
      pk.w[0] = cvtpk(hf[0], hf[1]);
      pk.w[1] = cvtpk(hf[2], hf[3]);
      *(u16x4*)(sHn + ef * 4096 + (wn * 64 + lp) * 8 + jo) = pk.q;
    }
  }
  __syncthreads();

  f32x4 aU[2][2];
#pragma unroll
  for (int nf = 0; nf < 2; ++nf)
#pragma unroll
    for (int ef = 0; ef < 2; ++ef) { aU[nf][ef][0]=0.f; aU[nf][ef][1]=0.f; aU[nf][ef][2]=0.f; aU[nf][ef][3]=0.f; }
#pragma unroll
  for (int kc = 0; kc < 8; ++kc) {
    short8 u0 = *(const short8*)(Urp + ((size_t)(kc * 16 + wn * 2 + 0) * 64 + lane) * 8);
    short8 u1 = *(const short8*)(Urp + ((size_t)(kc * 16 + wn * 2 + 1) * 64 + lane) * 8);
#pragma unroll
    for (int ef = 0; ef < 2; ++ef) {
      short8 hb = *(const short8*)(sHn + ef * 4096 + (kc * 64 + lane) * 8);
      aU[0][ef] = mfma16(u0, hb, aU[0][ef]);
      aU[1][ef] = mfma16(u1, hb, aU[1][ef]);
    }
  }
  // h natural write
  {
    const int r = tid >> 4;
    const int e = e0 + r;
#pragma unroll
    for (int it = 0; it < 2; ++it) {
      const int c = (tid & 15) * 8 + it * 128;
      const short8 val = *(const short8*)(sHn + (r >> 4) * 4096 +
                         (((c >> 5) * 64 + (r & 15) + 16 * ((c >> 3) & 3)) * 8));
      *(short8*)(HB + (size_t)e * 512 + c) = val;
    }
  }
  __syncthreads();   // all sHn reads (Ur GEMM + h write) done
#pragma unroll
  for (int nf = 0; nf < 2; ++nf) {
    const int lp = row0 + 16 * (nf * 2 + (kq >> 1));
    const int jo = 4 * (kq & 1);
#pragma unroll
    for (int ef = 0; ef < 2; ++ef) {
      union { unsigned w[2]; u16x4 q; } pk;
      pk.w[0] = cvtpk(aU[nf][ef][0], aU[nf][ef][1]);
      pk.w[1] = cvtpk(aU[nf][ef][2], aU[nf][ef][3]);
      *(u16x4*)(sHn + ef * 4096 + (wn * 64 + lp) * 8 + jo) = pk.q;
    }
  }
  __syncthreads();
  {
    const int r = tid >> 4;
    const int e = e0 + r;
#pragma unroll
    for (int it = 0; it < 2; ++it) {
      const int c = (tid & 15) * 8 + it * 128;
      const short8 val = *(const short8*)(sHn + (r >> 4) * 4096 +
                         (((c >> 5) * 64 + (r & 15) + 16 * ((c >> 3) & 3)) * 8));
      *(short8*)(HB + (size_t)e * 512 + 256 + c) = val;
    }
  }
}

// ---------------- readout ----------------
__global__ __launch_bounds__(256)
void readout(const u16* __restrict__ HB, const u16* __restrict__ fnp,
             const int* __restrict__ agraph, const u16* __restrict__ Wop,
             const float* __restrict__ bo, float* __restrict__ out) {
  __shared__ __align__(16) u16 sN[32][264];
  const int tid = threadIdx.x, wave = tid >> 6, lane = tid & 63;
  const int n0 = blockIdx.x * 32;
  const int row0 = lane & 15, kq = lane >> 4;

#pragma unroll 2
  for (int rr = 0; rr < 8; ++rr) {
    const int r = wave * 8 + rr;
    const int n = n0 + r;
    float s4[4] = {0.f, 0.f, 0.f, 0.f};
    if (n < NN) {
#pragma unroll
      for (int k = 0; k < 6; ++k) {
        const int idx = agraph[n * 6 + k];
        const u16x4 hv = *(const u16x4*)(HB + (size_t)idx * 512 + 4 * lane);
#pragma unroll
        for (int j = 0; j < 4; ++j) s4[j] += b2f(hv[j]);
      }
    }
#pragma unroll
    for (int j = 0; j < 4; ++j) sN[r][4 * lane + j] = f2b(s4[j]);
  }
  __syncthreads();

  f32x4 acc[2][4];
#pragma unroll
  for (int i = 0; i < 2; ++i)
#pragma unroll
    for (int n = 0; n < 4; ++n) { acc[i][n][0]=0.f; acc[i][n][1]=0.f; acc[i][n][2]=0.f; acc[i][n][3]=0.f; }
  const int ra = min(n0 + row0, NN - 1);
  const int rb = min(n0 + 16 + row0, NN - 1);
#pragma unroll
  for (int s = 0; s < 12; ++s) {
    short8 a0, a1;
    if (s < 4) {
      a0 = *(const short8*)(fnp + (size_t)ra * 128 + s * 32 + kq * 8);
      a1 = *(const short8*)(fnp + (size_t)rb * 128 + s * 32 + kq * 8);
    } else {
      a0 = *(const short8*)&sN[row0][(s - 4) * 32 + kq * 8];
      a1 = *(const short8*)&sN[row0 + 16][(s - 4) * 32 + kq * 8];
    }
#pragma unroll
    for (int ni = 0; ni < 4; ++ni) {
      short8 b = *(const short8*)(Wop + ((size_t)(s * 16 + wave * 4 + ni) * 64 + lane) * 8);
      acc[0][ni] = mfma16(a0, b, acc[0][ni]);
      acc[1][ni] = mfma16(a1, b, acc[1][ni]);
    }
  }
#pragma unroll
  for (int mi = 0; mi < 2; ++mi)
#pragma unroll
    for (int ni = 0; ni < 4; ++ni)
#pragma unroll
      for (int v = 0; v < 4; ++v) {
        const int m = mi * 16 + kq * 4 + v;
        const int col = wave * 64 + ni * 16 + row0;
        const int n = n0 + m;
        if (n < NN) {
          float val = fmaxf(acc[mi][ni][v] + bo[col], 0.f);
          if (n == 0) val = 0.f;             // n_mask
          out[(size_t)n * 256 + col] = val;
        }
      }
}

extern "C" void kernel_launch(void* const* d_in, const int* in_sizes, int n_in,
                              void* d_out, int out_size, void* d_ws, size_t ws_size,
                              hipStream_t stream) {
  const float* fnode      = (const float*)d_in[0];
  const int*   fmess_idx  = (const int*)d_in[1];
  const float* fmess_feat = (const float*)d_in[2];
  const int*   agraph     = (const int*)d_in[3];
  const int*   bgraph     = (const int*)d_in[4];
  const float* Wz         = (const float*)d_in[5];
  const float* bz         = (const float*)d_in[6];
  const float* Wr         = (const float*)d_in[7];
  const float* Ur         = (const float*)d_in[8];
  const float* bur        = (const float*)d_in[9];
  const float* Wh         = (const float*)d_in[10];
  const float* bh         = (const float*)d_in[11];
  const float* Wo         = (const float*)d_in[12];
  const float* bo         = (const float*)d_in[13];
  float* out = (float*)d_out;

  char* ws = (char*)d_ws;
  size_t off = 0;
  auto carve = [&](size_t bytes) -> char* {
    char* p = ws + off;
    off += (bytes + 511) & ~(size_t)511;
    return p;
  };
  u16* HB0  = (u16*)carve((size_t)NE * 512 * 2);
  u16* HB1  = (u16*)carve((size_t)NE * 512 * 2);
  u16* hmF  = (u16*)carve((size_t)NE * 128 * 2);
  u16* fnp  = (u16*)carve((size_t)NN * 128 * 2);
  u16* wpre = (u16*)carve((size_t)3 * 98304 * 2);
  u16* wgate= (u16*)carve((size_t)3 * 131072 * 2);
  u16* urp  = (u16*)carve((size_t)3 * 65536 * 2);
  u16* wop  = (u16*)carve((size_t)3 * 98304 * 2);
  if (off > ws_size) return;

  pack_wpre <<<dim3(384, 3), 256, 0, stream>>>(Wr, Wz, Wh, wpre);
  pack_wgate<<<dim3(512, 3), 256, 0, stream>>>(Wz, Wh, wgate);
  pack_ur   <<<dim3(256, 3), 256, 0, stream>>>(Ur, urp);
  pack_wo   <<<dim3(384, 3), 256, 0, stream>>>(Wo, wop);
  embed_hmess_f<<<NE / 2, 256, 0, stream>>>(fnode, fmess_idx, fmess_feat, hmF);
  embed_fnode<<<NN / 2, 256, 0, stream>>>(fnode, fnp);

  for (int g = 0; g < 3; ++g) {
    const u16* wpre_g  = wpre + (size_t)g * 98304;
    const u16* wgate_g = wgate + (size_t)g * 131072;
    const u16* urp_g   = urp + (size_t)g * 65536;
    const float* bur_g = bur + g * 256;
    const float* bz_g  = bz + g * 256;
    const float* bh_g  = bh + g * 256;
    step0<<<NE / 32, 512, 0, stream>>>(HB0, hmF, wpre_g, urp_g, bz_g, bh_g);
    u16* bufs[2] = {HB0, HB1};
    int cur = 0;
    for (int d = 1; d < 6; ++d) {
      mpn_fused<<<NE / 32, 512, 0, stream>>>(bufs[cur], bufs[1 - cur], hmF, bgraph,
                                             wpre_g, wgate_g, urp_g, bur_g, bz_g, bh_g);
      cur ^= 1;
    }
    readout<<<(NN + 31) / 32, 256, 0, stream>>>(
        bufs[cur], fnp, agraph, wop + (size_t)g * 98304, bo + g * 256, out + (size_t)g * NN * 256);
  }
}

// Round 20
// 3179.242 us; speedup vs baseline: 1.0080x; 1.0080x over previous
//
#include <hip/hip_runtime.h>

// D-MPNN (chemprop) x3 encoders on MI355X.
// R20 = R17 verbatim (proven best: 3185us total, mpn_fused 205us).
// Fused recompute of r1/zpre/hpre per step (no streamed intermediates),
// v_rcp/exp2 fast transcendentals with log2e folded into packed weights,
// r1 staged in sF sh-region. Balanced profile: HBM 29% / VALU 36% /
// MFMA 12% / Occ 42% -- latency-bound scattered gather, practical limit.

#define NE 100000   // messages
#define NN 50000    // nodes
#define L2E 1.4426950408889634f

typedef unsigned short u16;
typedef short short8 __attribute__((ext_vector_type(8)));
typedef float f32x4 __attribute__((ext_vector_type(4)));
typedef float floatx4 __attribute__((ext_vector_type(4)));
typedef unsigned short u16x4 __attribute__((ext_vector_type(4)));

__device__ __forceinline__ float b2f(u16 u) {
  union { unsigned int i; float f; } v; v.i = ((unsigned int)u) << 16; return v.f;
}
__device__ __forceinline__ u16 f2b(float f) {
  union { float f; unsigned int i; } v; v.f = f;
  unsigned int b = v.i;
  b += 0x7FFFu + ((b >> 16) & 1u);   // RTNE
  return (u16)(b >> 16);
}
__device__ __forceinline__ unsigned cvtpk(float lo, float hi) {
  unsigned r;
  asm("v_cvt_pk_bf16_f32 %0, %1, %2" : "=v"(r) : "v"(lo), "v"(hi));
  return r;
}
// arg prescaled by log2e: sigmoid(t) with x = log2e*t
__device__ __forceinline__ float sigm2(float x) {
  return __builtin_amdgcn_rcpf(1.0f + __builtin_amdgcn_exp2f(-x));
}
// arg prescaled by 2*log2e: tanh(t) with x = 2*log2e*t
__device__ __forceinline__ float tanh2(float x) {
  return 2.0f * __builtin_amdgcn_rcpf(1.0f + __builtin_amdgcn_exp2f(-x)) - 1.0f;
}
__device__ __forceinline__ f32x4 mfma16(short8 a, short8 b, f32x4 c) {
  return __builtin_amdgcn_mfma_f32_16x16x32_bf16(a, b, c, 0, 0, 0);
}

// ---------------- weight packing (fragment-major, log2e-scaled) ----------------
__global__ void pack_wpre(const float* __restrict__ Wr, const float* __restrict__ Wz,
                          const float* __restrict__ Wh, u16* __restrict__ dst) {
  const int g = blockIdx.y;
  const int p = blockIdx.x * 256 + threadIdx.x;           // < 98304  (K=128,N=768)
  const int j = p & 7, l = (p >> 3) & 63, q = p >> 9;
  const int nb = q % 48, s = q / 48;
  const int k = 32 * s + 8 * (l >> 4) + j;
  const int n = 16 * nb + (l & 15);
  float v = 0.f;
  if (k < 104) {
    if (n < 256)      v = Wr[((size_t)g * 104 + k) * 256 + n] * L2E;
    else if (n < 512) v = Wz[((size_t)g * 360 + k) * 256 + (n - 256)] * L2E;
    else              v = Wh[((size_t)g * 360 + k) * 256 + (n - 512)] * (2.0f * L2E);
  }
  dst[(size_t)g * 98304 + p] = f2b(v);
}

__global__ void pack_wgate(const float* __restrict__ Wz, const float* __restrict__ Wh,
                           u16* __restrict__ dst) {
  const int g = blockIdx.y;
  const int p = blockIdx.x * 256 + threadIdx.x;           // < 131072 (K=256,N=512)
  const int j = p & 7, l = (p >> 3) & 63, q = p >> 9;
  const int nb = q % 32, s = q / 32;
  const int k = 32 * s + 8 * (l >> 4) + j;
  const int n = 16 * nb + (l & 15);
  float v = (n < 256) ? Wz[((size_t)g * 360 + 104 + k) * 256 + n] * L2E
                      : Wh[((size_t)g * 360 + 104 + k) * 256 + (n - 256)] * (2.0f * L2E);
  dst[(size_t)g * 131072 + p] = f2b(v);
}

__global__ void pack_ur(const float* __restrict__ Ur, u16* __restrict__ dst) {
  const int g = blockIdx.y;
  const int p = blockIdx.x * 256 + threadIdx.x;           // < 65536 (K=256,N=256)
  const int j = p & 7, l = (p >> 3) & 63, q = p >> 9;
  const int nb = q % 16, s = q / 16;
  const int k = 32 * s + 8 * (l >> 4) + j;
  const int n = 16 * nb + (l & 15);
  dst[(size_t)g * 65536 + p] = f2b(Ur[((size_t)g * 256 + k) * 256 + n] * L2E);
}

__global__ void pack_wo(const float* __restrict__ Wo, u16* __restrict__ dst) {
  const int g = blockIdx.y;
  const int p = blockIdx.x * 256 + threadIdx.x;           // < 98304 (K=384,N=256)
  const int j = p & 7, l = (p >> 3) & 63, q = p >> 9;
  const int nb = q % 16, s = q / 16;
  const int k = 32 * s + 8 * (l >> 4) + j;
  const int n = 16 * nb + (l & 15);
  float v = 0.f;
  if (k < 98)        v = Wo[((size_t)g * 354 + k) * 256 + n];        // fnode part
  else if (k >= 128) v = Wo[((size_t)g * 354 + (k - 30)) * 256 + n]; // nei part
  dst[(size_t)g * 98304 + p] = f2b(v);
}

// ---------------- embeddings ----------------
__global__ void embed_hmess_f(const float* __restrict__ fnode, const int* __restrict__ fmess_idx,
                              const float* __restrict__ fmess_feat, u16* __restrict__ hmF) {
  const int e = blockIdx.x * 2 + (threadIdx.x >> 7);
  const int c = threadIdx.x & 127;
  const int src = fmess_idx[e * 2];
  float v = 0.f;
  if (c < 98)       v = fnode[(size_t)src * 98 + c];
  else if (c < 104) v = fmess_feat[(size_t)e * 6 + (c - 98)];
  hmF[(size_t)(e >> 4) * 2048 + ((c >> 5) * 64 + (e & 15) + 16 * ((c >> 3) & 3)) * 8 + (c & 7)] = f2b(v);
}

__global__ void embed_fnode(const float* __restrict__ fnode, u16* __restrict__ fnp) {
  const int n = blockIdx.x * 2 + (threadIdx.x >> 7);
  const int c = threadIdx.x & 127;
  float v = (c < 98) ? fnode[(size_t)n * 98 + c] : 0.f;
  fnp[(size_t)n * 128 + c] = f2b(v);
}

// ---------------- fused depth step (32 rows/block) ----------------
// aZ/aH accumulate hmess@Wpre (K=128, phase A) then sums@Wgate (K=256).
// r1 (+bur*L2E) staged in the sF sh-region (same frag addressing the gather
// uses), then overwritten by sh during gather.
__global__ __launch_bounds__(512, 4)
void mpn_fused(const u16* __restrict__ HBin, u16* __restrict__ HBout,
               const u16* __restrict__ hmF, const int* __restrict__ bgraph,
               const u16* __restrict__ Wpre, const u16* __restrict__ Wgate,
               const u16* __restrict__ Urp, const float* __restrict__ bur,
               const float* __restrict__ bz, const float* __restrict__ bh) {
  __shared__ __align__(16) u16 sF[16384];    // sh [0,8192), sg [8192,16384)
  const int tid = threadIdx.x;
  const int wn = tid >> 6, lane = tid & 63;
  const int row0 = lane & 15, kq = lane >> 4;
  const int e0 = blockIdx.x * 32;

  // ---- phase A: r1 / z-init / h-init from hmess (K=128) ----
  f32x4 aZ[2][2], aH[2][2], aR[2][2];
#pragma unroll
  for (int nf = 0; nf < 2; ++nf)
#pragma unroll
    for (int ef = 0; ef < 2; ++ef) {
      aZ[nf][ef][0]=0.f; aZ[nf][ef][1]=0.f; aZ[nf][ef][2]=0.f; aZ[nf][ef][3]=0.f;
      aH[nf][ef][0]=0.f; aH[nf][ef][1]=0.f; aH[nf][ef][2]=0.f; aH[nf][ef][3]=0.f;
      aR[nf][ef][0]=0.f; aR[nf][ef][1]=0.f; aR[nf][ef][2]=0.f; aR[nf][ef][3]=0.f;
    }
#pragma unroll
  for (int kc = 0; kc < 4; ++kc) {
    short8 bm[2];
#pragma unroll
    for (int ef = 0; ef < 2; ++ef)
      bm[ef] = *(const short8*)(hmF + (size_t)((e0 >> 4) + ef) * 2048 + (size_t)(kc * 64 + lane) * 8);
#pragma unroll
    for (int nf = 0; nf < 2; ++nf) {
      const int nb = wn * 2 + nf;
      short8 wr = *(const short8*)(Wpre + ((size_t)(kc * 48 + nb) * 64 + lane) * 8);
      short8 wz = *(const short8*)(Wpre + ((size_t)(kc * 48 + 16 + nb) * 64 + lane) * 8);
      short8 wh = *(const short8*)(Wpre + ((size_t)(kc * 48 + 32 + nb) * 64 + lane) * 8);
#pragma unroll
      for (int ef = 0; ef < 2; ++ef) {
        aR[nf][ef] = mfma16(wr, bm[ef], aR[nf][ef]);
        aZ[nf][ef] = mfma16(wz, bm[ef], aZ[nf][ef]);
        aH[nf][ef] = mfma16(wh, bm[ef], aH[nf][ef]);
      }
    }
  }
  // r1 (+bur*L2E) -> sh region of sF, frag layout
#pragma unroll
  for (int nf = 0; nf < 2; ++nf) {
    const int lp = row0 + 16 * (nf * 2 + (kq >> 1));
    const int jo = 4 * (kq & 1);
    const int n = wn * 32 + nf * 16 + kq * 4;
    const floatx4 bv = *(const floatx4*)(bur + n);
#pragma unroll
    for (int ef = 0; ef < 2; ++ef) {
      union { unsigned w[2]; u16x4 q; } pk;
      pk.w[0] = cvtpk(aR[nf][ef][0] + bv[0] * L2E, aR[nf][ef][1] + bv[1] * L2E);
      pk.w[1] = cvtpk(aR[nf][ef][2] + bv[2] * L2E, aR[nf][ef][3] + bv[3] * L2E);
      *(u16x4*)(sF + ef * 4096 + (wn * 64 + lp) * 8 + jo) = pk.q;
    }
  }
  __syncthreads();   // BA: r1 staged

  // ---- gather (natural lanes: full 512B row bursts); 4 rows/wave ----
  {
    const int c0 = 4 * lane;
    const int offc = ((c0 >> 5) * 64 + 16 * ((c0 >> 3) & 3)) * 8 + (c0 & 7);
#pragma unroll 2
    for (int rr = 0; rr < 4; ++rr) {
      const int r = wn * 4 + rr;
      const int e = e0 + r;
      const int off = (r >> 4) * 4096 + offc + (r & 15) * 8;
      const u16x4 r1v = *(const u16x4*)(sF + off);         // r1 from its own slot
      int idx[6];
#pragma unroll
      for (int k = 0; k < 6; ++k) idx[k] = bgraph[e * 6 + k];
      u16x4 hv[6], huv[6];
#pragma unroll
      for (int k = 0; k < 6; ++k) {
        const u16* rowp = HBin + (size_t)idx[k] * 512;
        hv[k]  = *(const u16x4*)(rowp + c0);
        huv[k] = *(const u16x4*)(rowp + 256 + c0);
      }
      float sh[4] = {0.f, 0.f, 0.f, 0.f}, sg[4] = {0.f, 0.f, 0.f, 0.f};
#pragma unroll
      for (int k = 0; k < 6; ++k)
#pragma unroll
        for (int j = 0; j < 4; ++j) {
          const float h  = b2f(hv[k][j]);
          const float rg = sigm2(b2f(r1v[j]) + b2f(huv[k][j]));
          sh[j] += h;
          sg[j] += rg * h;
        }
      union { unsigned w[2]; u16x4 q; } p0, p1;
      p0.w[0] = cvtpk(sh[0], sh[1]); p0.w[1] = cvtpk(sh[2], sh[3]);
      p1.w[0] = cvtpk(sg[0], sg[1]); p1.w[1] = cvtpk(sg[2], sg[3]);
      *(u16x4*)(sF + off) = p0.q;                          // overwrite r1 with sh
      *(u16x4*)(sF + 8192 + off) = p1.q;
    }
  }
  __syncthreads();   // B0: sF ready

  // ---- gate GEMMs: continue accumulating sums part (K=256) ----
#pragma unroll
  for (int kc = 0; kc < 8; ++kc) {
    short8 wz0 = *(const short8*)(Wgate + ((size_t)(kc * 32 + wn * 2 + 0) * 64 + lane) * 8);
    short8 wz1 = *(const short8*)(Wgate + ((size_t)(kc * 32 + wn * 2 + 1) * 64 + lane) * 8);
    short8 wh0 = *(const short8*)(Wgate + ((size_t)(kc * 32 + 16 + wn * 2 + 0) * 64 + lane) * 8);
    short8 wh1 = *(const short8*)(Wgate + ((size_t)(kc * 32 + 16 + wn * 2 + 1) * 64 + lane) * 8);
#pragma unroll
    for (int ef = 0; ef < 2; ++ef) {
      short8 bsh = *(const short8*)(sF + ef * 4096 + (kc * 64 + lane) * 8);
      short8 bsg = *(const short8*)(sF + 8192 + ef * 4096 + (kc * 64 + lane) * 8);
      aZ[0][ef] = mfma16(wz0, bsh, aZ[0][ef]);
      aZ[1][ef] = mfma16(wz1, bsh, aZ[1][ef]);
      aH[0][ef] = mfma16(wh0, bsg, aH[0][ef]);
      aH[1][ef] = mfma16(wh1, bsg, aH[1][ef]);
    }
  }

  // ---- GRU epilogue (scaled fp32 bias; shv from sF) ----
  u16x4 hq[2][2];
#pragma unroll
  for (int nf = 0; nf < 2; ++nf) {
    const int lp = row0 + 16 * (nf * 2 + (kq >> 1));
    const int jo = 4 * (kq & 1);
    const int n = wn * 32 + nf * 16 + kq * 4;
    const floatx4 bzv = *(const floatx4*)(bz + n);
    const floatx4 bhv = *(const floatx4*)(bh + n);
#pragma unroll
    for (int ef = 0; ef < 2; ++ef) {
      const int e = e0 + ef * 16 + row0;
      const int as = ef * 4096 + (wn * 64 + lp) * 8 + jo;
      const u16x4 shv = *(const u16x4*)(sF + as);
      float hf[4];
#pragma unroll
      for (int v = 0; v < 4; ++v) {
        const float z  = sigm2(aZ[nf][ef][v] + bzv[v] * L2E);
        const float ph = tanh2(aH[nf][ef][v] + bhv[v] * (2.0f * L2E));
        float h = (1.0f - z) * b2f(shv[v]) + z * ph;
        if (e == 0) h = 0.f;                  // e_mask
        hf[v] = h;
      }
      union { unsigned w[2]; u16x4 q; } pk;
      pk.w[0] = cvtpk(hf[0], hf[1]);
      pk.w[1] = cvtpk(hf[2], hf[3]);
      hq[nf][ef] = pk.q;
    }
  }
  __syncthreads();   // B1: all sF reads done -> safe to overwrite sg region

  // hnew frag into sg region
#pragma unroll
  for (int nf = 0; nf < 2; ++nf) {
    const int lp = row0 + 16 * (nf * 2 + (kq >> 1));
    const int jo = 4 * (kq & 1);
#pragma unroll
    for (int ef = 0; ef < 2; ++ef)
      *(u16x4*)(sF + 8192 + ef * 4096 + (wn * 64 + lp) * 8 + jo) = hq[nf][ef];
  }
  __syncthreads();   // B2: hnew frag ready

  // ---- hu^T = Urp x hnew (Urp log2e-scaled) ----
  f32x4 aU[2][2];
#pragma unroll
  for (int nf = 0; nf < 2; ++nf)
#pragma unroll
    for (int ef = 0; ef < 2; ++ef) { aU[nf][ef][0]=0.f; aU[nf][ef][1]=0.f; aU[nf][ef][2]=0.f; aU[nf][ef][3]=0.f; }
#pragma unroll
  for (int kc = 0; kc < 8; ++kc) {
    short8 u0 = *(const short8*)(Urp + ((size_t)(kc * 16 + wn * 2 + 0) * 64 + lane) * 8);
    short8 u1 = *(const short8*)(Urp + ((size_t)(kc * 16 + wn * 2 + 1) * 64 + lane) * 8);
#pragma unroll
    for (int ef = 0; ef < 2; ++ef) {
      short8 hb = *(const short8*)(sF + 8192 + ef * 4096 + (kc * 64 + lane) * 8);
      aU[0][ef] = mfma16(u0, hb, aU[0][ef]);
      aU[1][ef] = mfma16(u1, hb, aU[1][ef]);
    }
  }

  // h natural write (sg-region frag -> coalesced rows); 16 threads/row
  {
    const int r = tid >> 4;
    const int e = e0 + r;
#pragma unroll
    for (int it = 0; it < 2; ++it) {
      const int c = (tid & 15) * 8 + it * 128;
      const short8 val = *(const short8*)(sF + 8192 + (r >> 4) * 4096 +
                         (((c >> 5) * 64 + (r & 15) + 16 * ((c >> 3) & 3)) * 8));
      *(short8*)(HBout + (size_t)e * 512 + c) = val;
    }
  }
  // stage hu into sh region (dead since B1)
#pragma unroll
  for (int nf = 0; nf < 2; ++nf) {
    const int lp = row0 + 16 * (nf * 2 + (kq >> 1));
    const int jo = 4 * (kq & 1);
#pragma unroll
    for (int ef = 0; ef < 2; ++ef) {
      union { unsigned w[2]; u16x4 q; } pk;
      pk.w[0] = cvtpk(aU[nf][ef][0], aU[nf][ef][1]);
      pk.w[1] = cvtpk(aU[nf][ef][2], aU[nf][ef][3]);
      *(u16x4*)(sF + ef * 4096 + (wn * 64 + lp) * 8 + jo) = pk.q;
    }
  }
  __syncthreads();   // B3: hu frag ready

  // hu natural write
  {
    const int r = tid >> 4;
    const int e = e0 + r;
#pragma unroll
    for (int it = 0; it < 2; ++it) {
      const int c = (tid & 15) * 8 + it * 128;
      const short8 val = *(const short8*)(sF + (r >> 4) * 4096 +
                         (((c >> 5) * 64 + (r & 15) + 16 * ((c >> 3) & 3)) * 8));
      *(short8*)(HBout + (size_t)e * 512 + 256 + c) = val;
    }
  }
}

// ---------------- depth-0 (32 rows/block) ----------------
__global__ __launch_bounds__(512, 4)
void step0(u16* __restrict__ HB, const u16* __restrict__ hmF,
           const u16* __restrict__ Wpre, const u16* __restrict__ Urp,
           const float* __restrict__ bz, const float* __restrict__ bh) {
  __shared__ __align__(16) u16 sHn[8192];
  const int tid = threadIdx.x;
  const int wn = tid >> 6, lane = tid & 63;
  const int row0 = lane & 15, kq = lane >> 4;
  const int e0 = blockIdx.x * 32;

  f32x4 aZ[2][2], aH[2][2];
#pragma unroll
  for (int nf = 0; nf < 2; ++nf)
#pragma unroll
    for (int ef = 0; ef < 2; ++ef) {
      aZ[nf][ef][0]=0.f; aZ[nf][ef][1]=0.f; aZ[nf][ef][2]=0.f; aZ[nf][ef][3]=0.f;
      aH[nf][ef][0]=0.f; aH[nf][ef][1]=0.f; aH[nf][ef][2]=0.f; aH[nf][ef][3]=0.f;
    }
#pragma unroll
  for (int kc = 0; kc < 4; ++kc) {
    short8 bm[2];
#pragma unroll
    for (int ef = 0; ef < 2; ++ef)
      bm[ef] = *(const short8*)(hmF + (size_t)((e0 >> 4) + ef) * 2048 + (size_t)(kc * 64 + lane) * 8);
#pragma unroll
    for (int nf = 0; nf < 2; ++nf) {
      const int nb = wn * 2 + nf;
      short8 wz = *(const short8*)(Wpre + ((size_t)(kc * 48 + 16 + nb) * 64 + lane) * 8);
      short8 wh = *(const short8*)(Wpre + ((size_t)(kc * 48 + 32 + nb) * 64 + lane) * 8);
#pragma unroll
      for (int ef = 0; ef < 2; ++ef) {
        aZ[nf][ef] = mfma16(wz, bm[ef], aZ[nf][ef]);
        aH[nf][ef] = mfma16(wh, bm[ef], aH[nf][ef]);
      }
    }
  }

#pragma unroll
  for (int nf = 0; nf < 2; ++nf) {
    const int lp = row0 + 16 * (nf * 2 + (kq >> 1));
    const int jo = 4 * (kq & 1);
    const int n = wn * 32 + nf * 16 + kq * 4;
    const floatx4 bzv = *(const floatx4*)(bz + n);
    const floatx4 bhv = *(const floatx4*)(bh + n);
#pragma unroll
    for (int ef = 0; ef < 2; ++ef) {
      const int e = e0 + ef * 16 + row0;
      float hf[4];
#pragma unroll
      for (int v = 0; v < 4; ++v) {
        float h = sigm2(aZ[nf][ef][v] + bzv[v] * L2E) *
                  tanh2(aH[nf][ef][v] + bhv[v] * (2.0f * L2E));
        if (e == 0) h = 0.f;
        hf[v] = h;
      }
      union { unsigned w[2]; u16x4 q; } pk;
      pk.w[0] = cvtpk(hf[0], hf[1]);
      pk.w[1] = cvtpk(hf[2], hf[3]);
      *(u16x4*)(sHn + ef * 4096 + (wn * 64 + lp) * 8 + jo) = pk.q;
    }
  }
  __syncthreads();

  f32x4 aU[2][2];
#pragma unroll
  for (int nf = 0; nf < 2; ++nf)
#pragma unroll
    for (int ef = 0; ef < 2; ++ef) { aU[nf][ef][0]=0.f; aU[nf][ef][1]=0.f; aU[nf][ef][2]=0.f; aU[nf][ef][3]=0.f; }
#pragma unroll
  for (int kc = 0; kc < 8; ++kc) {
    short8 u0 = *(const short8*)(Urp + ((size_t)(kc * 16 + wn * 2 + 0) * 64 + lane) * 8);
    short8 u1 = *(const short8*)(Urp + ((size_t)(kc * 16 + wn * 2 + 1) * 64 + lane) * 8);
#pragma unroll
    for (int ef = 0; ef < 2; ++ef) {
      short8 hb = *(const short8*)(sHn + ef * 4096 + (kc * 64 + lane) * 8);
      aU[0][ef] = mfma16(u0, hb, aU[0][ef]);
      aU[1][ef] = mfma16(u1, hb, aU[1][ef]);
    }
  }
  // h natural write
  {
    const int r = tid >> 4;
    const int e = e0 + r;
#pragma unroll
    for (int it = 0; it < 2; ++it) {
      const int c = (tid & 15) * 8 + it * 128;
      const short8 val = *(const short8*)(sHn + (r >> 4) * 4096 +
                         (((c >> 5) * 64 + (r & 15) + 16 * ((c >> 3) & 3)) * 8));
      *(short8*)(HB + (size_t)e * 512 + c) = val;
    }
  }
  __syncthreads();   // all sHn reads (Ur GEMM + h write) done
#pragma unroll
  for (int nf = 0; nf < 2; ++nf) {
    const int lp = row0 + 16 * (nf * 2 + (kq >> 1));
    const int jo = 4 * (kq & 1);
#pragma unroll
    for (int ef = 0; ef < 2; ++ef) {
      union { unsigned w[2]; u16x4 q; } pk;
      pk.w[0] = cvtpk(aU[nf][ef][0], aU[nf][ef][1]);
      pk.w[1] = cvtpk(aU[nf][ef][2], aU[nf][ef][3]);
      *(u16x4*)(sHn + ef * 4096 + (wn * 64 + lp) * 8 + jo) = pk.q;
    }
  }
  __syncthreads();
  {
    const int r = tid >> 4;
    const int e = e0 + r;
#pragma unroll
    for (int it = 0; it < 2; ++it) {
      const int c = (tid & 15) * 8 + it * 128;
      const short8 val = *(const short8*)(sHn + (r >> 4) * 4096 +
                         (((c >> 5) * 64 + (r & 15) + 16 * ((c >> 3) & 3)) * 8));
      *(short8*)(HB + (size_t)e * 512 + 256 + c) = val;
    }
  }
}

// ---------------- readout ----------------
__global__ __launch_bounds__(256)
void readout(const u16* __restrict__ HB, const u16* __restrict__ fnp,
             const int* __restrict__ agraph, const u16* __restrict__ Wop,
             const float* __restrict__ bo, float* __restrict__ out) {
  __shared__ __align__(16) u16 sN[32][264];
  const int tid = threadIdx.x, wave = tid >> 6, lane = tid & 63;
  const int n0 = blockIdx.x * 32;
  const int row0 = lane & 15, kq = lane >> 4;

#pragma unroll 2
  for (int rr = 0; rr < 8; ++rr) {
    const int r = wave * 8 + rr;
    const int n = n0 + r;
    float s4[4] = {0.f, 0.f, 0.f, 0.f};
    if (n < NN) {
#pragma unroll
      for (int k = 0; k < 6; ++k) {
        const int idx = agraph[n * 6 + k];
        const u16x4 hv = *(const u16x4*)(HB + (size_t)idx * 512 + 4 * lane);
#pragma unroll
        for (int j = 0; j < 4; ++j) s4[j] += b2f(hv[j]);
      }
    }
#pragma unroll
    for (int j = 0; j < 4; ++j) sN[r][4 * lane + j] = f2b(s4[j]);
  }
  __syncthreads();

  f32x4 acc[2][4];
#pragma unroll
  for (int i = 0; i < 2; ++i)
#pragma unroll
    for (int n = 0; n < 4; ++n) { acc[i][n][0]=0.f; acc[i][n][1]=0.f; acc[i][n][2]=0.f; acc[i][n][3]=0.f; }
  const int ra = min(n0 + row0, NN - 1);
  const int rb = min(n0 + 16 + row0, NN - 1);
#pragma unroll
  for (int s = 0; s < 12; ++s) {
    short8 a0, a1;
    if (s < 4) {
      a0 = *(const short8*)(fnp + (size_t)ra * 128 + s * 32 + kq * 8);
      a1 = *(const short8*)(fnp + (size_t)rb * 128 + s * 32 + kq * 8);
    } else {
      a0 = *(const short8*)&sN[row0][(s - 4) * 32 + kq * 8];
      a1 = *(const short8*)&sN[row0 + 16][(s - 4) * 32 + kq * 8];
    }
#pragma unroll
    for (int ni = 0; ni < 4; ++ni) {
      short8 b = *(const short8*)(Wop + ((size_t)(s * 16 + wave * 4 + ni) * 64 + lane) * 8);
      acc[0][ni] = mfma16(a0, b, acc[0][ni]);
      acc[1][ni] = mfma16(a1, b, acc[1][ni]);
    }
  }
#pragma unroll
  for (int mi = 0; mi < 2; ++mi)
#pragma unroll
    for (int ni = 0; ni < 4; ++ni)
#pragma unroll
      for (int v = 0; v < 4; ++v) {
        const int m = mi * 16 + kq * 4 + v;
        const int col = wave * 64 + ni * 16 + row0;
        const int n = n0 + m;
        if (n < NN) {
          float val = fmaxf(acc[mi][ni][v] + bo[col], 0.f);
          if (n == 0) val = 0.f;             // n_mask
          out[(size_t)n * 256 + col] = val;
        }
      }
}

extern "C" void kernel_launch(void* const* d_in, const int* in_sizes, int n_in,
                              void* d_out, int out_size, void* d_ws, size_t ws_size,
                              hipStream_t stream) {
  const float* fnode      = (const float*)d_in[0];
  const int*   fmess_idx  = (const int*)d_in[1];
  const float* fmess_feat = (const float*)d_in[2];
  const int*   agraph     = (const int*)d_in[3];
  const int*   bgraph     = (const int*)d_in[4];
  const float* Wz         = (const float*)d_in[5];
  const float* bz         = (const float*)d_in[6];
  const float* Wr         = (const float*)d_in[7];
  const float* Ur         = (const float*)d_in[8];
  const float* bur        = (const float*)d_in[9];
  const float* Wh         = (const float*)d_in[10];
  const float* bh         = (const float*)d_in[11];
  const float* Wo         = (const float*)d_in[12];
  const float* bo         = (const float*)d_in[13];
  float* out = (float*)d_out;

  char* ws = (char*)d_ws;
  size_t off = 0;
  auto carve = [&](size_t bytes) -> char* {
    char* p = ws + off;
    off += (bytes + 511) & ~(size_t)511;
    return p;
  };
  u16* HB0  = (u16*)carve((size_t)NE * 512 * 2);
  u16* HB1  = (u16*)carve((size_t)NE * 512 * 2);
  u16* hmF  = (u16*)carve((size_t)NE * 128 * 2);
  u16* fnp  = (u16*)carve((size_t)NN * 128 * 2);
  u16* wpre = (u16*)carve((size_t)3 * 98304 * 2);
  u16* wgate= (u16*)carve((size_t)3 * 131072 * 2);
  u16* urp  = (u16*)carve((size_t)3 * 65536 * 2);
  u16* wop  = (u16*)carve((size_t)3 * 98304 * 2);
  if (off > ws_size) return;

  pack_wpre <<<dim3(384, 3), 256, 0, stream>>>(Wr, Wz, Wh, wpre);
  pack_wgate<<<dim3(512, 3), 256, 0, stream>>>(Wz, Wh, wgate);
  pack_ur   <<<dim3(256, 3), 256, 0, stream>>>(Ur, urp);
  pack_wo   <<<dim3(384, 3), 256, 0, stream>>>(Wo, wop);
  embed_hmess_f<<<NE / 2, 256, 0, stream>>>(fnode, fmess_idx, fmess_feat, hmF);
  embed_fnode<<<NN / 2, 256, 0, stream>>>(fnode, fnp);

  for (int g = 0; g < 3; ++g) {
    const u16* wpre_g  = wpre + (size_t)g * 98304;
    const u16* wgate_g = wgate + (size_t)g * 131072;
    const u16* urp_g   = urp + (size_t)g * 65536;
    const float* bur_g = bur + g * 256;
    const float* bz_g  = bz + g * 256;
    const float* bh_g  = bh + g * 256;
    step0<<<NE / 32, 512, 0, stream>>>(HB0, hmF, wpre_g, urp_g, bz_g, bh_g);
    u16* bufs[2] = {HB0, HB1};
    int cur = 0;
    for (int d = 1; d < 6; ++d) {
      mpn_fused<<<NE / 32, 512, 0, stream>>>(bufs[cur], bufs[1 - cur], hmF, bgraph,
                                             wpre_g, wgate_g, urp_g, bur_g, bz_g, bh_g);
      cur ^= 1;
    }
    readout<<<(NN + 31) / 32, 256, 0, stream>>>(
        bufs[cur], fnp, agraph, wop + (size_t)g * 98304, bo + g * 256, out + (size_t)g * NN * 256);
  }
}